// Round 1
// baseline (233.582 us; speedup 1.0000x reference)
//
#include <hip/hip_runtime.h>
#include <cstdint>

#define T_TOK 4096
#define HID 2048
#define NH 16
#define NKV 4
#define HD 128
#define WIN 1024
#define QKVO 3072

typedef float f32x4 __attribute__((ext_vector_type(4)));
typedef __bf16 bf16x8 __attribute__((ext_vector_type(8)));
typedef __bf16 bf16x4 __attribute__((ext_vector_type(4)));
typedef __bf16 bf16x2 __attribute__((ext_vector_type(2)));

__device__ __forceinline__ void gload16(const void* g, void* lds) {
  auto gp = reinterpret_cast<__attribute__((address_space(1))) void*>(
      reinterpret_cast<uintptr_t>(g));
  auto lp = reinterpret_cast<__attribute__((address_space(3))) void*>(
      reinterpret_cast<uintptr_t>(lds));
  __builtin_amdgcn_global_load_lds(gp, lp, 16, 0, 0);
}

__device__ __forceinline__ f32x4 mfma16(bf16x8 a, bf16x8 b, f32x4 c) {
  return __builtin_amdgcn_mfma_f32_16x16x32_bf16(a, b, c, 0, 0, 0);
}

// ---------------- fp32 -> bf16 elementwise (hidden) ----------------
__global__ __launch_bounds__(256) void k_f32_to_bf16(const float* __restrict__ x,
                                                     __bf16* __restrict__ y) {
  const size_t e = (size_t)blockIdx.x * 256 + threadIdx.x;  // 8 elems each
  const float4* xv = (const float4*)x;
  float4 a = xv[e * 2], b = xv[e * 2 + 1];
  bf16x8 o;
  o[0] = (__bf16)a.x; o[1] = (__bf16)a.y; o[2] = (__bf16)a.z; o[3] = (__bf16)a.w;
  o[4] = (__bf16)b.x; o[5] = (__bf16)b.y; o[6] = (__bf16)b.z; o[7] = (__bf16)b.w;
  *(bf16x8*)(y + e * 8) = o;
}

// ---------------- fp32 [R][C] -> bf16 [C][R] transpose ----------------
__global__ __launch_bounds__(256) void k_transpose(const float* __restrict__ W,
                                                   __bf16* __restrict__ Wt,
                                                   int R, int C) {
  __shared__ __bf16 tb[32][33];
  const int nbx = C >> 5;
  const int c0 = (blockIdx.x % nbx) << 5;
  const int r0 = (blockIdx.x / nbx) << 5;
  const int tx = threadIdx.x & 31, ty = threadIdx.x >> 5;  // ty 0..7
#pragma unroll
  for (int i = 0; i < 32; i += 8)
    tb[ty + i][tx] = (__bf16)W[(size_t)(r0 + ty + i) * C + c0 + tx];
  __syncthreads();
#pragma unroll
  for (int i = 0; i < 32; i += 8)
    Wt[(size_t)(c0 + ty + i) * R + r0 + tx] = tb[tx][ty + i];
}

// ---------------- RoPE cos/sin tables ----------------
__global__ void k_rope_tab(const int* __restrict__ pos, float* __restrict__ cosT,
                           float* __restrict__ sinT) {
  const int t = blockIdx.x;
  const int d = threadIdx.x;  // 0..63
  const float inv = exp2f(-(float)d * (16.609640474436812f / 64.0f));  // theta^-d/64
  const float fr = (float)pos[t] * inv;
  cosT[t * 64 + d] = cosf(fr);
  sinT[t * 64 + d] = sinf(fr);
}

// ---------------- 128x128-tile bf16 GEMM (m97 structure) ----------------
// C[M][N] (fp32, +optional bias) = A[M][K] * Bt[N][K]^T
template <bool BIAS>
__global__ __launch_bounds__(256, 2) void k_gemm(const __bf16* __restrict__ A,
                                                 const __bf16* __restrict__ Bt,
                                                 const float* __restrict__ bias,
                                                 float* __restrict__ C,
                                                 int M, int N, int K) {
  __shared__ __align__(16) __bf16 As[128 * 32];
  __shared__ __align__(16) __bf16 Bs[128 * 32];
  const int tid = threadIdx.x;
  const int lane = tid & 63;
  const int w = tid >> 6;
  const int wr = w >> 1, wc = w & 1;
  const int c = lane & 15, g = lane >> 4;

  const int nbx = N >> 7;
  const int bx = blockIdx.x % nbx;
  const int by = blockIdx.x / nbx;
  const int m0 = by << 7, n0 = bx << 7;

  // staging: wave w owns tile bytes [w*2048, w*2048+2048), 2 x 1KB loads
  const int o0 = w * 2048 + lane * 16;
  const int r0 = o0 >> 6, cb0 = o0 & 63;
  const int o1 = o0 + 1024;
  const int r1 = o1 >> 6, cb1 = o1 & 63;
  const __bf16* gA0 = A + (size_t)(m0 + r0) * K + (cb0 >> 1);
  const __bf16* gA1 = A + (size_t)(m0 + r1) * K + (cb1 >> 1);
  const __bf16* gB0 = Bt + (size_t)(n0 + r0) * K + (cb0 >> 1);
  const __bf16* gB1 = Bt + (size_t)(n0 + r1) * K + (cb1 >> 1);
  char* lA0 = (char*)As + w * 2048;
  char* lA1 = lA0 + 1024;
  char* lB0 = (char*)Bs + w * 2048;
  char* lB1 = lB0 + 1024;

  f32x4 acc[4][4] = {};

  for (int kt = 0; kt < K; kt += 32) {
    __syncthreads();
    gload16(gA0 + kt, lA0);
    gload16(gA1 + kt, lA1);
    gload16(gB0 + kt, lB0);
    gload16(gB1 + kt, lB1);
    __syncthreads();
    bf16x8 af[4], bfr[4];
#pragma unroll
    for (int mi = 0; mi < 4; mi++)
      af[mi] = *(const bf16x8*)(As + ((wr * 64 + mi * 16 + c) * 32 + g * 8));
#pragma unroll
    for (int ni = 0; ni < 4; ni++)
      bfr[ni] = *(const bf16x8*)(Bs + ((wc * 64 + ni * 16 + c) * 32 + g * 8));
#pragma unroll
    for (int mi = 0; mi < 4; mi++)
#pragma unroll
      for (int ni = 0; ni < 4; ni++)
        acc[mi][ni] = mfma16(af[mi], bfr[ni], acc[mi][ni]);
  }

#pragma unroll
  for (int ni = 0; ni < 4; ni++) {
    const int col = n0 + wc * 64 + ni * 16 + c;
    const float bv = BIAS ? bias[col] : 0.0f;
#pragma unroll
    for (int mi = 0; mi < 4; mi++)
#pragma unroll
      for (int r = 0; r < 4; r++) {
        const int row = m0 + wr * 64 + mi * 16 + 4 * g + r;
        C[(size_t)row * N + col] = acc[mi][ni][r] + bv;
      }
  }
}

// ---------------- RoPE + pack: qkv fp32 -> Qp/Kp (roped bf16), Vt (transposed bf16)
__global__ __launch_bounds__(256) void k_rope_pack(
    const float* __restrict__ qkv, const float* __restrict__ cosT,
    const float* __restrict__ sinT, __bf16* __restrict__ Qp,
    __bf16* __restrict__ Kp, __bf16* __restrict__ Vt) {
  const int t0 = blockIdx.x * 64;
  const int hh = blockIdx.y;  // 0..23: 16 q heads, 4 k heads, 4 v heads
  const int tid = threadIdx.x;
  const int col0 = hh * HD;
  __shared__ __bf16 lt[64][136];
  if (hh < NH + NKV) {
    const bool isq = hh < NH;
    const float s = isq ? 0.08838834764831845f : 1.0f;  // 1/sqrt(128) folded into Q
    __bf16* base = isq ? (Qp + (size_t)hh * T_TOK * HD)
                       : (Kp + (size_t)(hh - NH) * T_TOK * HD);
#pragma unroll
    for (int jj = 0; jj < 16; jj++) {
      const int e = jj * 256 + tid;  // 64 t x 64 d2
      const int tl = e >> 6, d2 = e & 63;
      const int tt = t0 + tl;
      const float x1 = qkv[(size_t)tt * QKVO + col0 + d2];
      const float x2 = qkv[(size_t)tt * QKVO + col0 + 64 + d2];
      const float cs = cosT[tt * 64 + d2];
      const float sn = sinT[tt * 64 + d2];
      __bf16* dst = base + (size_t)tt * HD;
      dst[d2] = (__bf16)((x1 * cs - x2 * sn) * s);
      dst[64 + d2] = (__bf16)((x2 * cs + x1 * sn) * s);
    }
  } else {
    const int kv = hh - (NH + NKV);
#pragma unroll
    for (int jj = 0; jj < 32; jj++) {
      const int e = jj * 256 + tid;  // 64 t x 128 d
      const int tl = e >> 7, d = e & 127;
      lt[tl][d] = (__bf16)qkv[(size_t)(t0 + tl) * QKVO + col0 + d];
    }
    __syncthreads();
#pragma unroll
    for (int jj = 0; jj < 32; jj++) {
      const int e = jj * 256 + tid;  // 128 d x 64 t
      const int d = e >> 6, tl = e & 63;
      Vt[((size_t)kv * HD + d) * T_TOK + t0 + tl] = lt[tl][d];
    }
  }
}

// ---------------- flash attention, sliding window, GQA ----------------
// block: (q-tile of 64 rows) x (head). 4 waves, wave w owns q rows [q0+16w, +16).
// Swapped QK^T: S^T = K*Q^T so softmax row (fixed q) is lane-local (q = lane&15).
__global__ __launch_bounds__(256, 2) void k_attn(const __bf16* __restrict__ Qp,
                                                 const __bf16* __restrict__ Kp,
                                                 const __bf16* __restrict__ Vt,
                                                 __bf16* __restrict__ attnO) {
  __shared__ __align__(16) __bf16 Ks[32 * 136];    // [32 keys][128 d], 272B row pitch
  __shared__ __align__(16) __bf16 Vs[128 * 40];    // [128 d][32 keys], 80B row pitch
  __shared__ __align__(16) __bf16 Ps[4][16 * 40];  // per wave: [16 q][32 keys], 80B pitch

  const int tid = threadIdx.x;
  const int lane = tid & 63;
  const int w = tid >> 6;
  const int c = lane & 15, g = lane >> 4;
  const int qb = blockIdx.x;
  const int h = blockIdx.y;
  const int kvh = h >> 2;  // GQA group of 4
  const int q0 = qb * 64;
  const int i_row = q0 + w * 16 + c;  // this lane's query row

  bf16x8 qf[4];  // Q B-fragments: col=q(=c), k = 32*ds + 8*g + j
  {
    const __bf16* qbase = Qp + ((size_t)h * T_TOK + i_row) * HD;
#pragma unroll
    for (int ds = 0; ds < 4; ds++) qf[ds] = *(const bf16x8*)(qbase + ds * 32 + g * 8);
  }

  f32x4 ot[8] = {};  // O^T: ot[m][r] -> d = 16m+4g+r, q = c
  float mrun = -1e30f, lrun = 0.0f;

  const int jstart = (q0 >= WIN) ? (q0 - WIN) : 0;
  const int jend = q0 + 64;
  const __bf16* Kbase = Kp + (size_t)kvh * T_TOK * HD;
  const __bf16* Vbase = Vt + (size_t)kvh * HD * T_TOK;

  for (int j0 = jstart; j0 < jend; j0 += 32) {
    __syncthreads();
#pragma unroll
    for (int i = 0; i < 2; i++) {  // K chunk [32][128]
      const int e = i * 256 + tid;
      const int row = e >> 4, gb = (e & 15) * 16;
      int4 val = *(const int4*)(Kbase + (size_t)(j0 + row) * HD + (gb >> 1));
      *(int4*)((char*)Ks + row * 272 + gb) = val;
    }
#pragma unroll
    for (int i = 0; i < 2; i++) {  // V^T chunk [128][32]
      const int e = i * 256 + tid;
      const int row = e >> 2, gb = (e & 3) * 16;
      int4 val = *(const int4*)(Vbase + (size_t)row * T_TOK + j0 + (gb >> 1));
      *(int4*)((char*)Vs + row * 80 + gb) = val;
    }
    __syncthreads();

    // S^T = K * Q^T : D[key][q], 2 key tiles x 4 d-steps
    f32x4 st[2] = {};
#pragma unroll
    for (int t = 0; t < 2; t++)
#pragma unroll
      for (int ds = 0; ds < 4; ds++) {
        bf16x8 kf = *(const bf16x8*)((char*)Ks + (t * 16 + c) * 272 + ds * 64 + g * 16);
        st[t] = mfma16(kf, qf[ds], st[t]);
      }

    // mask + online softmax. lane: q=c; keys j0 + 16t + 4g + r
    float p[8];
    float cmax = -1e30f;
#pragma unroll
    for (int t = 0; t < 2; t++)
#pragma unroll
      for (int r = 0; r < 4; r++) {
        const int j = j0 + t * 16 + 4 * g + r;
        float s = st[t][r];
        const bool ok = (j <= i_row) && (i_row - j <= WIN);
        s = ok ? s : -1e30f;
        p[t * 4 + r] = s;
        cmax = fmaxf(cmax, s);
      }
    cmax = fmaxf(cmax, __shfl_xor(cmax, 16));
    cmax = fmaxf(cmax, __shfl_xor(cmax, 32));
    const float mn = fmaxf(mrun, cmax);
    const float alpha = __expf(mrun - mn);  // fully-masked prefix self-heals (alpha->0 later)
    float rs = 0.0f;
#pragma unroll
    for (int x = 0; x < 8; x++) {
      const float e_ = __expf(p[x] - mn);
      p[x] = e_;
      rs += e_;
    }
    rs += __shfl_xor(rs, 16);
    rs += __shfl_xor(rs, 32);
    lrun = lrun * alpha + rs;
    mrun = mn;
#pragma unroll
    for (int m = 0; m < 8; m++) ot[m] *= alpha;

    // P -> per-wave LDS, re-read as MFMA B-fragment (col=q, k=key)
    char* pw = (char*)&Ps[w][0];
#pragma unroll
    for (int t = 0; t < 2; t++)
#pragma unroll
      for (int r2 = 0; r2 < 4; r2 += 2) {
        bf16x2 pk;
        pk[0] = (__bf16)p[t * 4 + r2];
        pk[1] = (__bf16)p[t * 4 + r2 + 1];
        *(bf16x2*)(pw + c * 80 + (t * 16 + 4 * g + r2) * 2) = pk;
      }
    bf16x8 pf = *(const bf16x8*)(pw + c * 80 + g * 16);

    // O^T += V^T * P^T : 8 d-tiles
#pragma unroll
    for (int m = 0; m < 8; m++) {
      bf16x8 vf = *(const bf16x8*)((char*)Vs + (m * 16 + c) * 80 + g * 16);
      ot[m] = mfma16(vf, pf, ot[m]);
    }
  }

  const float inv_l = 1.0f / lrun;
  __bf16* orow = attnO + (size_t)i_row * (NH * HD) + h * HD;
#pragma unroll
  for (int m = 0; m < 8; m++) {
    bf16x4 o4;
#pragma unroll
    for (int r = 0; r < 4; r++) o4[r] = (__bf16)(ot[m][r] * inv_l);
    *(bf16x4*)(orow + m * 16 + 4 * g) = o4;
  }
}

// ---------------- launcher ----------------
extern "C" void kernel_launch(void* const* d_in, const int* in_sizes, int n_in,
                              void* d_out, int out_size, void* d_ws, size_t ws_size,
                              hipStream_t stream) {
  (void)in_sizes; (void)n_in; (void)out_size; (void)ws_size;
  const float* hidden = (const float*)d_in[0];
  const int* positions = (const int*)d_in[1];
  const float* w_qkv = (const float*)d_in[2];
  const float* b_qkv = (const float*)d_in[3];
  const float* w_o = (const float*)d_in[4];
  float* out = (float*)d_out;

  char* ws = (char*)d_ws;
  __bf16* Hb = (__bf16*)ws;    ws += (size_t)T_TOK * HID * 2;        // 16 MB
  __bf16* Wqkvt = (__bf16*)ws; ws += (size_t)QKVO * HID * 2;         // 12 MB
  __bf16* Wot = (__bf16*)ws;   ws += (size_t)HID * HID * 2;          // 8 MB
  float* cosT = (float*)ws;    ws += (size_t)T_TOK * 64 * 4;         // 1 MB
  float* sinT = (float*)ws;    ws += (size_t)T_TOK * 64 * 4;         // 1 MB
  float* qkv = (float*)ws;     ws += (size_t)T_TOK * QKVO * 4;       // 48 MB
  __bf16* Qp = (__bf16*)ws;    ws += (size_t)NH * T_TOK * HD * 2;    // 16 MB
  __bf16* Kp = (__bf16*)ws;    ws += (size_t)NKV * T_TOK * HD * 2;   // 4 MB
  __bf16* Vt = (__bf16*)ws;    ws += (size_t)NKV * HD * T_TOK * 2;   // 4 MB
  __bf16* attnb = (__bf16*)ws; ws += (size_t)T_TOK * NH * HD * 2;    // 16 MB

  k_f32_to_bf16<<<T_TOK * HID / (256 * 8), 256, 0, stream>>>(hidden, Hb);
  k_transpose<<<(QKVO / 32) * (HID / 32), 256, 0, stream>>>(w_qkv, Wqkvt, HID, QKVO);
  k_transpose<<<(HID / 32) * (HID / 32), 256, 0, stream>>>(w_o, Wot, HID, HID);
  k_rope_tab<<<T_TOK, 64, 0, stream>>>(positions, cosT, sinT);
  k_gemm<true><<<(T_TOK / 128) * (QKVO / 128), 256, 0, stream>>>(
      Hb, Wqkvt, b_qkv, qkv, T_TOK, QKVO, HID);
  k_rope_pack<<<dim3(T_TOK / 64, NH + 2 * NKV), 256, 0, stream>>>(
      qkv, cosT, sinT, Qp, Kp, Vt);
  k_attn<<<dim3(T_TOK / 64, NH), 256, 0, stream>>>(Qp, Kp, Vt, attnb);
  k_gemm<false><<<(T_TOK / 128) * (HID / 128), 256, 0, stream>>>(
      attnb, Wot, nullptr, out, T_TOK, HID, HID);
}